// Round 5
// baseline (1923.078 us; speedup 1.0000x reference)
//
#include <hip/hip_runtime.h>
#include <math.h>

// Weighted cross-entropy: out[n] = -w[target[n]] * (logits[n,target[n]] - logsumexp(logits[n,:]))
// N = 8192 rows, C = 50257 classes, fp32. Single-pass online logsumexp.
// Memory-bound: 1.647 GB mandatory read -> ~261 us floor @ 6.3 TB/s.

#define CLS 50257
#define BLOCK 256

__global__ __launch_bounds__(BLOCK) void ce_loss_kernel(
    const float* __restrict__ logits,
    const int*   __restrict__ target,
    const float* __restrict__ cw,
    float*       __restrict__ out)
{
    const int row = blockIdx.x;
    const float* __restrict__ rp = logits + (size_t)row * CLS;
    const int tid = threadIdx.x;

    // Row base element index = row*CLS; CLS is odd so rows are only 16B-aligned
    // when row%4==0. Peel `lead` scalars to reach float4 alignment.
    const int lead = (4 - (((unsigned)row * (unsigned)CLS) & 3u)) & 3u;

    float m = -INFINITY;   // running max
    float s = 0.0f;        // running sum of exp(x - m)

    // leading scalars (0..3 of them)
    if (tid < lead) {
        m = rp[tid];
        s = 1.0f;
    }

    // vectorized body: float4 loads, fully coalesced (64 lanes x 16B = 1KB/instr)
    const int nvec = (CLS - lead) >> 2;
    const float4* __restrict__ vp = (const float4*)(rp + lead);
    #pragma unroll 2
    for (int i = tid; i < nvec; i += BLOCK) {
        float4 v = vp[i];
        float mx = fmaxf(fmaxf(v.x, v.y), fmaxf(v.z, v.w));
        if (mx > m) {                    // rare after warm-up: one rescale
            s *= __expf(m - mx);         // m=-inf first time: 0*0 = 0, OK
            m = mx;
        }
        s += __expf(v.x - m) + __expf(v.y - m) +
             __expf(v.z - m) + __expf(v.w - m);
    }

    // tail scalars (CLS - lead - 4*nvec elements, 0..3 of them)
    for (int i = lead + (nvec << 2) + tid; i < CLS; i += BLOCK) {
        float x = rp[i];
        if (x > m) { s *= __expf(m - x); m = x; s += 1.0f; }
        else       { s += __expf(x - m); }
    }

    // wave (64-lane) butterfly merge of (m, s)
    #pragma unroll
    for (int off = 32; off > 0; off >>= 1) {
        float om = __shfl_xor(m, off);
        float os = __shfl_xor(s, off);
        float nm = fmaxf(m, om);
        s = s * __expf(m - nm) + os * __expf(om - nm);
        m = nm;
    }

    // cross-wave merge via LDS (4 waves)
    __shared__ float sm[BLOCK / 64];
    __shared__ float ss[BLOCK / 64];
    const int wave = tid >> 6;
    const int lane = tid & 63;
    if (lane == 0) { sm[wave] = m; ss[wave] = s; }
    __syncthreads();

    if (tid == 0) {
        float M = sm[0], S = ss[0];
        #pragma unroll
        for (int w = 1; w < BLOCK / 64; ++w) {
            float nm = fmaxf(M, sm[w]);
            S = S * __expf(M - nm) + ss[w] * __expf(sm[w] - nm);
            M = nm;
        }
        const int t = target[row];
        const float xt = rp[t];                 // gather target logit (L2/L3 hit)
        out[row] = -cw[t] * (xt - (M + logf(S)));
    }
}

extern "C" void kernel_launch(void* const* d_in, const int* in_sizes, int n_in,
                              void* d_out, int out_size, void* d_ws, size_t ws_size,
                              hipStream_t stream) {
    const float* logits = (const float*)d_in[0];
    const int*   target = (const int*)d_in[1];   // jax int64 with x64 disabled -> int32
    const float* cw     = (const float*)d_in[2];
    float*       out    = (float*)d_out;

    const int N = in_sizes[1];                   // 8192 rows (target has N elements)
    ce_loss_kernel<<<N, BLOCK, 0, stream>>>(logits, target, cw, out);
}